// Round 3
// baseline (117.939 us; speedup 1.0000x reference)
//
#include <hip/hip_runtime.h>

// Problem constants (match reference)
#define B 8
#define S 2048
#define N 512
#define D 1024
#define MAX_W 32
#define MASK_FILL -1000.0f

typedef float vfloat4 __attribute__((ext_vector_type(4)));
// amdgcn builtins (cvt_pkrtz, fdot2) traffic in __fp16 vectors
typedef __fp16 half2v __attribute__((ext_vector_type(2)));
typedef unsigned int uint;

// pack two f32 -> f16x2 (v_cvt_pkrtz_f16_f32)
__device__ inline uint pack_f16x2(float x, float y) {
#if __has_builtin(__builtin_amdgcn_cvt_pkrtz)
    half2v r = __builtin_amdgcn_cvt_pkrtz(x, y);
    return __builtin_bit_cast(uint, r);
#else
    half2v r; r[0] = (__fp16)x; r[1] = (__fp16)y;
    return __builtin_bit_cast(uint, r);
#endif
}

// f16x2 dot with f32 accumulator: v_dot2_f32_f16 (1 instr = 2 FMA)
__device__ inline float dot2(uint a, uint b, float c) {
    half2v x = __builtin_bit_cast(half2v, a);
    half2v y = __builtin_bit_cast(half2v, b);
#if __has_builtin(__builtin_amdgcn_fdot2)
    return __builtin_amdgcn_fdot2(x, y, c, false);
#else
    return c + (float)x[0] * (float)y[0] + (float)x[1] * (float)y[1];
#endif
}

// ---------------------------------------------------------------------------
// Kernel 1 (prep): logits + fp16 compression of seq, one pass over seq.
// HBM-bound: 64 MB read + 32 MB write ~= 15 us floor — at it (R0/R2 micro-
// changes were zero-delta). Unchanged this round.
// ---------------------------------------------------------------------------
__global__ __launch_bounds__(512) void prep_kernel(
    const float* __restrict__ seq,
    const float* __restrict__ att_w,
    const float* __restrict__ att_b,
    float* __restrict__ logits,
    unsigned short* __restrict__ seqh)
{
    const int row  = blockIdx.x * 8 + (threadIdx.x >> 6);   // 8 waves/block
    const int lane = threadIdx.x & 63;

    const float4* rp = (const float4*)(seq + (size_t)row * D);
    const float4* wp = (const float4*)att_w;

    float4 a[4];
    float acc = 0.0f;
#pragma unroll
    for (int k = 0; k < 4; ++k) {
        a[k] = rp[lane + 64 * k];
        const float4 w = wp[lane + 64 * k];
        acc += a[k].x * w.x + a[k].y * w.y + a[k].z * w.z + a[k].w * w.w;
    }

    uint2* hp = (uint2*)(seqh + (size_t)row * D);
#pragma unroll
    for (int k = 0; k < 4; ++k) {
        uint2 h;
        h.x = pack_f16x2(a[k].x, a[k].y);
        h.y = pack_f16x2(a[k].z, a[k].w);
        hp[lane + 64 * k] = h;
    }

#pragma unroll
    for (int off = 32; off > 0; off >>= 1)
        acc += __shfl_down(acc, off);
    if (lane == 0)
        logits[row] = acc + att_b[0];
}

// ---------------------------------------------------------------------------
// Kernel 2 (R14): ONE WAVE PER SPAN — zero LDS, zero barriers.
// R13 post-mortem: dot2 (halved VALU) was zero-delta => pool is NOT
// VALU-bound. New theory: latency/serialization-bound (barrier-fenced
// softmax head + short barrier-fenced main loop, ~5 blocks/CU). Fix:
//   - 4 independent spans per 256-thr block (same batch -> XCD affinity,
//     nwg = 1024, %8 == 0), each span owned by one wave-synchronous wave.
//   - softmax in lanes 0..31 (width-32 shuffles); attn/offsets live in
//     registers, broadcast via __shfl — no LDS, no __syncthreads at all.
//   - lane c owns 16 B slices at f16 cols [8c,8c+8) and [512+8c,...);
//     rows in (r,r+1) pairs -> proven perm + v_dot2_f32_f16 path.
//   - trip rounded to 2 (was 8): ~18% less padded-row gather traffic.
//   - next-pair prefetch keeps 4 loads in flight per wave; 16 waves/CU
//     of independent spans hide L2 latency.
// Predicted: if pool was latency-bound ~35-40us -> ~6-10us, total ->
// ~90-100us. If total unchanged ~116.5: fixed harness floor confirmed.
// ---------------------------------------------------------------------------
__global__ __launch_bounds__(256) void pool_kernel(
    const unsigned short* __restrict__ seqh,
    const int*   __restrict__ spans,
    const float* __restrict__ logits,
    float* __restrict__ out)
{
    const int b    = blockIdx.x & 7;                    // batch -> XCD affinity
    const int wid  = threadIdx.x >> 6;                  // wave id 0..3
    const int n    = (blockIdx.x >> 3) * 4 + wid;       // span within batch
    const int span = b * N + n;
    const int lane = threadIdx.x & 63;

    const int start = spans[2 * span + 0];
    const int end   = spans[2 * span + 1];              // inclusive
    const int width = end - start;                      // valid = width + 1

    // ---- softmax head, lanes 0..31 meaningful (wave-synchronous) ----
    const int  w     = lane;
    const int  raw   = end - w;
    const bool valid = (w <= width) && (raw >= 0);
    // valid: raw >= start -> idx = raw (matches reference). padded: weight
    // exactly 0; point at start (in-span row, cache-hit dup).
    const int idx = raw > start ? raw : start;
    const float l = valid ? logits[b * S + idx] : MASK_FILL;

    float m = l;
#pragma unroll
    for (int off = 16; off > 0; off >>= 1)
        m = fmaxf(m, __shfl_down(m, off, 32));
    m = __shfl(m, 0, 32);

    const float p = __expf(l - m);

    float sum = p;
#pragma unroll
    for (int off = 16; off > 0; off >>= 1)
        sum += __shfl_down(sum, off, 32);
    sum = __shfl(sum, 0, 32);

    const float at = p / sum;                           // exactly 0 if masked
    // even lane r holds half2(attn[r], attn[r+1]); row byte-offset per lane
    const uint ah2  = pack_f16x2(at, __shfl_down(at, 1, 32));
    const uint offr = (uint)idx << 11;                  // idx * D * 2 bytes

    // ---- main loop: row pairs, 4x 16B loads/pair, perm+dot2 ----
    const char* sb  = (const char*)seqh + (size_t)b * S * D * 2;
    const uint  cvo = (uint)lane * 16u;                 // 16 B slice owner

    float acc[16];
#pragma unroll
    for (int j = 0; j < 16; ++j) acc[j] = 0.0f;

    const int cnt   = width + 1;                        // wave-uniform
    const int pairs = (cnt + 1) >> 1;                   // 1..16

#define LDROW(OFF, ADD) (*(const uint4*)(sb + (OFF) + cvo + (ADD)))

    uint o0 = __shfl(offr, 0);
    uint o1 = __shfl(offr, 1);
    uint4 qa0 = LDROW(o0, 0);        // row r,   cols [8c, 8c+8)
    uint4 qb0 = LDROW(o0, 1024);     // row r,   cols [512+8c, ...)
    uint4 qa1 = LDROW(o1, 0);        // row r+1
    uint4 qb1 = LDROW(o1, 1024);

    for (int pp = 0; pp < pairs; ++pp) {
        const uint ah = __shfl(ah2, 2 * pp);            // (attn[r], attn[r+1])

        uint4 na0, nb0, na1, nb1;
        const bool more = (pp + 1) < pairs;             // wave-uniform
        if (more) {
            const uint m0 = __shfl(offr, 2 * pp + 2);
            const uint m1 = __shfl(offr, 2 * pp + 3);
            na0 = LDROW(m0, 0);
            nb0 = LDROW(m0, 1024);
            na1 = LDROW(m1, 0);
            nb1 = LDROW(m1, 1024);
        }

        // perm(S0=qy,S1=qx,0x05040100) -> half2(qx.h0, qy.h0)  (even dim)
        // perm(S0=qy,S1=qx,0x07060302) -> half2(qx.h1, qy.h1)  (odd dim)
#define PAIR(qx, qy, jlo, jhi)                                              \
        acc[jlo] = dot2(ah, __builtin_amdgcn_perm(qy, qx, 0x05040100u),     \
                        acc[jlo]);                                          \
        acc[jhi] = dot2(ah, __builtin_amdgcn_perm(qy, qx, 0x07060302u),     \
                        acc[jhi]);

        PAIR(qa0.x, qa1.x,  0,  1)
        PAIR(qa0.y, qa1.y,  2,  3)
        PAIR(qa0.z, qa1.z,  4,  5)
        PAIR(qa0.w, qa1.w,  6,  7)
        PAIR(qb0.x, qb1.x,  8,  9)
        PAIR(qb0.y, qb1.y, 10, 11)
        PAIR(qb0.z, qb1.z, 12, 13)
        PAIR(qb0.w, qb1.w, 14, 15)
#undef PAIR

        if (more) { qa0 = na0; qb0 = nb0; qa1 = na1; qb1 = nb1; }
    }
#undef LDROW

    // ---- store: lane c owns f32 cols [8c,8c+8) and [512+8c,512+8c+8) ----
    float* orow = out + (size_t)span * D;
    vfloat4 v;
    v.x = acc[0];  v.y = acc[1];  v.z = acc[2];  v.w = acc[3];
    __builtin_nontemporal_store(v, (vfloat4*)(orow + 8 * lane));
    v.x = acc[4];  v.y = acc[5];  v.z = acc[6];  v.w = acc[7];
    __builtin_nontemporal_store(v, (vfloat4*)(orow + 8 * lane + 4));
    v.x = acc[8];  v.y = acc[9];  v.z = acc[10]; v.w = acc[11];
    __builtin_nontemporal_store(v, (vfloat4*)(orow + 512 + 8 * lane));
    v.x = acc[12]; v.y = acc[13]; v.z = acc[14]; v.w = acc[15];
    __builtin_nontemporal_store(v, (vfloat4*)(orow + 512 + 8 * lane + 4));
}

// ---------------------------------------------------------------------------
extern "C" void kernel_launch(void* const* d_in, const int* in_sizes, int n_in,
                              void* d_out, int out_size, void* d_ws, size_t ws_size,
                              hipStream_t stream)
{
    const float* seq    = (const float*)d_in[0];  // (B,S,D) f32
    const int*   spans  = (const int*)  d_in[1];  // (B,N,2) i32
    const float* att_w  = (const float*)d_in[2];  // (D,1)   f32
    const float* att_b  = (const float*)d_in[3];  // (1,)    f32

    float* out    = (float*)d_out;                // (B,N,D) f32
    float* logits = (float*)d_ws;                 // (B,S)   f32   (64 KB)
    unsigned short* seqh =
        (unsigned short*)((char*)d_ws + (size_t)B * S * sizeof(float)); // 32 MB f16

    prep_kernel<<<(B * S) / 8, 512, 0, stream>>>(seq, att_w, att_b,
                                                 logits, seqh);
    pool_kernel<<<(B * N) / 4, 256, 0, stream>>>(seqh, spans, logits, out);
}